// Round 1
// baseline (5046.425 us; speedup 1.0000x reference)
//
#include <hip/hip_runtime.h>
#include <math.h>

// Batched Jonker-Volgenant LAP solver, one block per batch element.
// N = 256 rows/cols, B = 256 problems. Exactly mirrors the reference's
// shortest-augmenting-path algorithm (scipy linear_sum_assignment).

#define LAP_N 256

__global__ __launch_bounds__(256, 1) void lap_solve(const float* __restrict__ D,
                                                    float* __restrict__ partial) {
    const int b = blockIdx.x;
    const int t = threadIdx.x;              // thread t owns column t (and row t where relevant)
    const float* __restrict__ C = D + (size_t)b * LAP_N * LAP_N;

    __shared__ float u[LAP_N], v[LAP_N], spc[LAP_N];
    __shared__ int   path[LAP_N], col4row[LAP_N], row4col[LAP_N];
    __shared__ unsigned char SR[LAP_N], SC[LAP_N];
    __shared__ float s_minval;
    __shared__ int   s_i, s_sink;
    __shared__ float rv[4];
    __shared__ int   ri[4];

    u[t] = 0.0f; v[t] = 0.0f; col4row[t] = -1; row4col[t] = -1;
    __syncthreads();

    for (int cur_row = 0; cur_row < LAP_N; ++cur_row) {
        // ---- init Dijkstra state for this row ----
        spc[t] = INFINITY; path[t] = -1; SR[t] = 0; SC[t] = 0;
        if (t == 0) { s_minval = 0.0f; s_i = cur_row; s_sink = -1; }
        __syncthreads();

        // ---- shortest augmenting path search ----
        for (;;) {
            const int   i      = s_i;
            const float minVal = s_minval;
            if (t == i) SR[t] = 1;
            const float ui = u[i];

            // relax column t through row i (reduced cost), skip visited cols
            const bool notSC = (SC[t] == 0);
            float r = minVal + C[i * LAP_N + t] - ui - v[t];
            if (notSC && r < spc[t]) { spc[t] = r; path[t] = i; }

            // masked argmin over columns (lowest index on ties, like jnp.argmin)
            float bv = notSC ? spc[t] : INFINITY;
            int   bi = t;
            #pragma unroll
            for (int off = 32; off > 0; off >>= 1) {
                float ov = __shfl_down(bv, off);
                int   oi = __shfl_down(bi, off);
                if (ov < bv || (ov == bv && oi < bi)) { bv = ov; bi = oi; }
            }
            if ((t & 63) == 0) { rv[t >> 6] = bv; ri[t >> 6] = bi; }
            __syncthreads();

            if (t == 0) {
                float val = rv[0]; int j = ri[0];
                #pragma unroll
                for (int w = 1; w < 4; ++w) {
                    float ov = rv[w]; int oi = ri[w];
                    if (ov < val || (ov == val && oi < j)) { val = ov; j = oi; }
                }
                s_minval = val;
                SC[j] = 1;
                const int rj = row4col[j];
                if (rj < 0) s_sink = j; else s_i = rj;
            }
            __syncthreads();
            if (s_sink >= 0) break;
        }

        // ---- dual variable update (scipy-identical) ----
        {
            const float minVal = s_minval;
            if (t == cur_row)      u[t] += minVal;
            else if (SR[t])        u[t] += minVal - spc[col4row[t]];
            if (SC[t])             v[t] += spc[t] - minVal;
        }
        __syncthreads();

        // ---- augment along predecessor path (sequential, thread 0) ----
        if (t == 0) {
            int j = s_sink;
            for (;;) {
                const int ii = path[j];
                row4col[j] = ii;
                const int jn = col4row[ii];
                col4row[ii] = j;
                if (ii == cur_row) break;
                j = jn;
            }
        }
        __syncthreads();
    }

    // ---- per-sample mean of matched costs ----
    float s = C[t * LAP_N + col4row[t]];
    #pragma unroll
    for (int off = 32; off > 0; off >>= 1) s += __shfl_down(s, off);
    if ((t & 63) == 0) rv[t >> 6] = s;
    __syncthreads();
    if (t == 0) partial[b] = (rv[0] + rv[1] + rv[2] + rv[3]) * (1.0f / LAP_N);
}

__global__ __launch_bounds__(256, 1) void reduce_final(const float* __restrict__ partial,
                                                       float* __restrict__ out, int B) {
    const int t = threadIdx.x;
    __shared__ float rv[4];
    float s = (t < B) ? partial[t] : 0.0f;
    #pragma unroll
    for (int off = 32; off > 0; off >>= 1) s += __shfl_down(s, off);
    if ((t & 63) == 0) rv[t >> 6] = s;
    __syncthreads();
    if (t == 0) out[0] = (rv[0] + rv[1] + rv[2] + rv[3]) / (float)B;
}

extern "C" void kernel_launch(void* const* d_in, const int* in_sizes, int n_in,
                              void* d_out, int out_size, void* d_ws, size_t ws_size,
                              hipStream_t stream) {
    const float* D = (const float*)d_in[0];
    float* out = (float*)d_out;
    float* partial = (float*)d_ws;           // B floats of scratch

    const int B = in_sizes[0] / (LAP_N * LAP_N);   // 256

    lap_solve<<<B, LAP_N, 0, stream>>>(D, partial);
    reduce_final<<<1, 256, 0, stream>>>(partial, out, B);
}

// Round 2
// 1817.687 us; speedup vs baseline: 2.7763x; 2.7763x over previous
//
#include <hip/hip_runtime.h>
#include <math.h>

// Batched Jonker-Volgenant LAP solver, ONE WAVE (64 lanes) per problem.
// Lane l owns columns 4l..4l+3; per-column state (v, spc, path, row4col, SC)
// lives in registers. Initialization: column reduction + greedy assignment
// (exact-optimum preserving), then shortest-augmenting-path for free rows.
// Inner Dijkstra loop has NO barriers (single-wave, shuffle-based argmin).

#define LAP_N 256

__global__ __launch_bounds__(64, 1) void lap_solve(const float* __restrict__ D,
                                                   float* __restrict__ partial) {
    const int b    = blockIdx.x;
    const int lane = threadIdx.x;                       // 0..63
    const float* __restrict__ C = D + (size_t)b * LAP_N * LAP_N;

    __shared__ __align__(16) float u[LAP_N];
    __shared__ __align__(16) float spc_lds[LAP_N];
    __shared__ __align__(16) int   path_lds[LAP_N];
    __shared__ __align__(16) int   col4row[LAP_N];      // col assigned to row, -1 free
    __shared__ __align__(16) int   vis[LAP_N];          // visited-row list per search
    __shared__ __align__(16) int   rowclaim[LAP_N];

    // ---- phase 0: column reduction (v_j = min_i C[i][j], argmin row) ----
    float v0 = INFINITY, v1 = INFINITY, v2 = INFINITY, v3 = INFINITY;
    int   a0 = 0, a1 = 0, a2 = 0, a3 = 0;
    #pragma unroll 8
    for (int i = 0; i < LAP_N; ++i) {
        float4 c = *(const float4*)(C + (size_t)i * LAP_N + 4 * lane);
        if (c.x < v0) { v0 = c.x; a0 = i; }
        if (c.y < v1) { v1 = c.y; a1 = i; }
        if (c.z < v2) { v2 = c.z; a2 = i; }
        if (c.w < v3) { v3 = c.w; a3 = i; }
    }

    for (int k = lane; k < LAP_N; k += 64) {
        u[k] = 0.0f; col4row[k] = -1; rowclaim[k] = 0x7fffffff;
    }
    __syncthreads();

    // ---- phase 1: greedy assignment on tight edges (deterministic via atomicMin) ----
    atomicMin(&rowclaim[a0], 4 * lane + 0);
    atomicMin(&rowclaim[a1], 4 * lane + 1);
    atomicMin(&rowclaim[a2], 4 * lane + 2);
    atomicMin(&rowclaim[a3], 4 * lane + 3);
    __syncthreads();

    int r0 = -1, r1 = -1, r2 = -1, r3 = -1;             // row4col for owned cols
    if (rowclaim[a0] == 4 * lane + 0) { r0 = a0; col4row[a0] = 4 * lane + 0; }
    if (rowclaim[a1] == 4 * lane + 1) { r1 = a1; col4row[a1] = 4 * lane + 1; }
    if (rowclaim[a2] == 4 * lane + 2) { r2 = a2; col4row[a2] = 4 * lane + 2; }
    if (rowclaim[a3] == 4 * lane + 3) { r3 = a3; col4row[a3] = 4 * lane + 3; }
    __syncthreads();

    // ---- phase 2: shortest augmenting path for each free row ----
    for (int cur = 0; cur < LAP_N; ++cur) {
        if (col4row[cur] >= 0) continue;                // uniform

        float sp0 = INFINITY, sp1 = INFINITY, sp2 = INFINITY, sp3 = INFINITY;
        int   p0 = -1, p1 = -1, p2 = -1, p3 = -1;
        int   scm    = 0;                               // SC bits for owned cols
        float minVal = 0.0f;
        int   i      = cur;
        int   nvis   = 0;
        int   sink   = -1;

        for (;;) {
            if (lane == 0) vis[nvis] = i;
            ++nvis;
            float  ui = u[i];                                        // uniform LDS read
            float4 c  = *(const float4*)(C + (size_t)i * LAP_N + 4 * lane);
            float base = minVal - ui;
            float r;
            r = base + c.x - v0; if (!(scm & 1) && r < sp0) { sp0 = r; p0 = i; }
            r = base + c.y - v1; if (!(scm & 2) && r < sp1) { sp1 = r; p1 = i; }
            r = base + c.z - v2; if (!(scm & 4) && r < sp2) { sp2 = r; p2 = i; }
            r = base + c.w - v3; if (!(scm & 8) && r < sp3) { sp3 = r; p3 = i; }

            // local argmin over 4 owned cols (lowest slot on ties)
            float bv = (scm & 1) ? INFINITY : sp0;
            int   bs = 0;
            float t;
            t = (scm & 2) ? INFINITY : sp1; if (t < bv) { bv = t; bs = 1; }
            t = (scm & 4) ? INFINITY : sp2; if (t < bv) { bv = t; bs = 2; }
            t = (scm & 8) ? INFINITY : sp3; if (t < bv) { bv = t; bs = 3; }

            // wave-wide min (value only), then owner = lowest lane attaining it
            float m = bv;
            m = fminf(m, __shfl_xor(m, 1));
            m = fminf(m, __shfl_xor(m, 2));
            m = fminf(m, __shfl_xor(m, 4));
            m = fminf(m, __shfl_xor(m, 8));
            m = fminf(m, __shfl_xor(m, 16));
            m = fminf(m, __shfl_xor(m, 32));
            unsigned long long msk = __ballot(bv == m);
            int owner = (int)__builtin_ctzll(msk);

            int rjc  = (bs == 0) ? r0 : ((bs == 1) ? r1 : ((bs == 2) ? r2 : r3));
            int rj   = __shfl(rjc, owner);              // row4col[j]
            int bs_o = __shfl(bs, owner);
            int j    = (owner << 2) + bs_o;

            minVal = m;
            if (lane == owner) scm |= (1 << bs);
            if (rj < 0) { sink = j; break; }
            i = rj;
        }

        // dump per-col spc/path to LDS for the cross-lane phases
        *(float4*)(&spc_lds[4 * lane]) = make_float4(sp0, sp1, sp2, sp3);
        *(int4*)(&path_lds[4 * lane])  = make_int4(p0, p1, p2, p3);
        __syncthreads();

        // ---- dual update (scipy-identical) ----
        for (int k = lane; k < nvis; k += 64) {
            int rr = vis[k];
            if (rr != cur) u[rr] += minVal - spc_lds[col4row[rr]];
        }
        if (lane == 0) u[cur] += minVal;
        if (scm & 1) v0 += sp0 - minVal;
        if (scm & 2) v1 += sp1 - minVal;
        if (scm & 4) v2 += sp2 - minVal;
        if (scm & 8) v3 += sp3 - minVal;
        __syncthreads();   // dual reads of col4row must finish before augment writes

        // ---- augment along predecessor path (wave-uniform walk) ----
        int j = sink;
        for (;;) {
            int ii = path_lds[j];                       // uniform
            if (lane == (j >> 2)) {                     // row4col[j] = ii (register)
                int sl = j & 3;
                if      (sl == 0) r0 = ii;
                else if (sl == 1) r1 = ii;
                else if (sl == 2) r2 = ii;
                else              r3 = ii;
            }
            int jn = col4row[ii];                       // read old value first
            if (lane == 0) col4row[ii] = j;
            if (ii == cur) break;
            j = jn;
        }
        __syncthreads();
    }

    // ---- per-sample mean of matched costs ----
    float sum = 0.0f;
    #pragma unroll
    for (int k = 0; k < 4; ++k) {
        int rr = lane + 64 * k;
        int jj = col4row[rr];
        sum += C[(size_t)rr * LAP_N + jj];
    }
    sum += __shfl_xor(sum, 1);
    sum += __shfl_xor(sum, 2);
    sum += __shfl_xor(sum, 4);
    sum += __shfl_xor(sum, 8);
    sum += __shfl_xor(sum, 16);
    sum += __shfl_xor(sum, 32);
    if (lane == 0) partial[b] = sum * (1.0f / LAP_N);
}

__global__ __launch_bounds__(256, 1) void reduce_final(const float* __restrict__ partial,
                                                       float* __restrict__ out, int B) {
    const int t = threadIdx.x;
    __shared__ float rv[4];
    float s = (t < B) ? partial[t] : 0.0f;
    #pragma unroll
    for (int off = 32; off > 0; off >>= 1) s += __shfl_down(s, off);
    if ((t & 63) == 0) rv[t >> 6] = s;
    __syncthreads();
    if (t == 0) out[0] = (rv[0] + rv[1] + rv[2] + rv[3]) / (float)B;
}

extern "C" void kernel_launch(void* const* d_in, const int* in_sizes, int n_in,
                              void* d_out, int out_size, void* d_ws, size_t ws_size,
                              hipStream_t stream) {
    const float* D = (const float*)d_in[0];
    float* out = (float*)d_out;
    float* partial = (float*)d_ws;                      // B floats of scratch

    const int B = in_sizes[0] / (LAP_N * LAP_N);        // 256

    lap_solve<<<B, 64, 0, stream>>>(D, partial);
    reduce_final<<<1, 256, 0, stream>>>(partial, out, B);
}

// Round 3
// 1083.296 us; speedup vs baseline: 4.6584x; 1.6779x over previous
//
#include <hip/hip_runtime.h>

// Batched integer Jonker-Volgenant LAP, one wave64 per problem.
// Cost matrix quantized to u16 (round-to-nearest, eps=2^-17) and staged in
// LDS (128 KB); the solve is EXACT integer arithmetic on the quantized
// matrix (optimal matching for Q => suboptimality on C <= 2*n*eps, far under
// the output threshold). Final loss is evaluated on the ORIGINAL fp32 data.
// Init: column reduction + greedy claim + JV augmenting-row-reduction
// (2 passes), then shortest-augmenting-path searches with a DPP-based
// packed (value<<8|col) wave argmin. Lane l owns columns 4l..4l+3.

#define N 256
typedef unsigned int u32;

static __device__ __forceinline__ u32 umin2(u32 a, u32 b) { return a < b ? a : b; }
static __device__ __forceinline__ u32 umax2(u32 a, u32 b) { return a < b ? b : a; }

template <int CTRL, int RM>
static __device__ __forceinline__ u32 dppmin(u32 x) {
    u32 t = (u32)__builtin_amdgcn_update_dpp((int)x, (int)x, CTRL, RM, 0xF, false);
    return umin2(x, t);
}

// full-wave min of packed u32; returns broadcast scalar (valid in all lanes)
static __device__ __forceinline__ u32 wave_min64(u32 x) {
    x = dppmin<0xB1, 0xF>(x);    // quad_perm [1,0,3,2]  (xor 1)
    x = dppmin<0x4E, 0xF>(x);    // quad_perm [2,3,0,1]  (xor 2)
    x = dppmin<0x141, 0xF>(x);   // row_half_mirror      (xor-ish 4)
    x = dppmin<0x140, 0xF>(x);   // row_mirror           (xor-ish 8)
    x = dppmin<0x142, 0xA>(x);   // bcast15 -> rows 1,3
    x = dppmin<0x143, 0x8>(x);   // bcast31 -> row 3
    return (u32)__builtin_amdgcn_readlane((int)x, 63);
}

template <int CTRL, int RM>
static __device__ __forceinline__ void dpp2min(u32& p1, u32& p2) {
    u32 b1 = (u32)__builtin_amdgcn_update_dpp((int)p1, (int)p1, CTRL, RM, 0xF, false);
    u32 b2 = (u32)__builtin_amdgcn_update_dpp((int)p2, (int)p2, CTRL, RM, 0xF, false);
    u32 lo = umin2(p1, b1), hi = umax2(p1, b1);
    p1 = lo;
    p2 = umin2(umin2(p2, b2), hi);
}

// two smallest packed values across the wave (disjoint per-lane sets);
// results valid in lane 63 only -> readlane-broadcast.
static __device__ __forceinline__ void wave_min2_64(u32& P1, u32& P2) {
    u32 p1 = P1, p2 = P2;
    dpp2min<0xB1, 0xF>(p1, p2);
    dpp2min<0x4E, 0xF>(p1, p2);
    dpp2min<0x141, 0xF>(p1, p2);
    dpp2min<0x140, 0xF>(p1, p2);
    dpp2min<0x142, 0xA>(p1, p2);
    dpp2min<0x143, 0x8>(p1, p2);
    P1 = (u32)__builtin_amdgcn_readlane((int)p1, 63);
    P2 = (u32)__builtin_amdgcn_readlane((int)p2, 63);
}

__global__ __launch_bounds__(64, 1) void lap_solve(const float* __restrict__ D,
                                                   float* __restrict__ partial) {
    const int b = blockIdx.x;
    const int lane = threadIdx.x;
    const int c0 = 4 * lane;                       // first owned column
    const float* __restrict__ C = D + (size_t)b * N * N;

    __shared__ unsigned short Q[N * N];            // 128 KB quantized costs
    __shared__ int u_lds[N], col4row[N], row4col[N];
    __shared__ int spc_lds[N], path_lds[N], vis[N], fA[N], fB[N], claim[N];

    // ---- phase 0: stage + quantize + column minima ----
    int v0 = 0x7fffffff, v1 = 0x7fffffff, v2 = 0x7fffffff, v3 = 0x7fffffff;
    int a0 = 0, a1 = 0, a2 = 0, a3 = 0;
    #pragma unroll 4
    for (int i = 0; i < N; ++i) {
        float4 c = *(const float4*)(C + (size_t)i * N + c0);
        int q0 = min(65535, max(0, (int)fmaf(c.x, 65536.0f, 0.5f)));
        int q1 = min(65535, max(0, (int)fmaf(c.y, 65536.0f, 0.5f)));
        int q2 = min(65535, max(0, (int)fmaf(c.z, 65536.0f, 0.5f)));
        int q3 = min(65535, max(0, (int)fmaf(c.w, 65536.0f, 0.5f)));
        *(ushort4*)(Q + i * N + c0) = make_ushort4((unsigned short)q0, (unsigned short)q1,
                                                   (unsigned short)q2, (unsigned short)q3);
        if (q0 < v0) { v0 = q0; a0 = i; }
        if (q1 < v1) { v1 = q1; a1 = i; }
        if (q2 < v2) { v2 = q2; a2 = i; }
        if (q3 < v3) { v3 = q3; a3 = i; }
    }
    for (int k = lane; k < N; k += 64) { u_lds[k] = 0; col4row[k] = -1; claim[k] = 0x7fffffff; }
    __syncthreads();

    // ---- phase 1: greedy claim on tight edges (lowest col wins a row) ----
    atomicMin(&claim[a0], c0 + 0);
    atomicMin(&claim[a1], c0 + 1);
    atomicMin(&claim[a2], c0 + 2);
    atomicMin(&claim[a3], c0 + 3);
    __syncthreads();
    int r0 = (claim[a0] == c0 + 0) ? a0 : -1; if (r0 >= 0) col4row[a0] = c0 + 0;
    int r1 = (claim[a1] == c0 + 1) ? a1 : -1; if (r1 >= 0) col4row[a1] = c0 + 1;
    int r2 = (claim[a2] == c0 + 2) ? a2 : -1; if (r2 >= 0) col4row[a2] = c0 + 2;
    int r3 = (claim[a3] == c0 + 3) ? a3 : -1; if (r3 >= 0) col4row[a3] = c0 + 3;
    row4col[c0 + 0] = r0; row4col[c0 + 1] = r1;
    row4col[c0 + 2] = r2; row4col[c0 + 3] = r3;
    __syncthreads();

    // ---- build free-row list (ascending, via wave prefix sum) ----
    int nfree;
    {
        int4 cc = *(const int4*)&col4row[c0];
        int f0 = (cc.x < 0), f1 = (cc.y < 0), f2 = (cc.z < 0), f3 = (cc.w < 0);
        int cnt = f0 + f1 + f2 + f3;
        int inc = cnt;
        #pragma unroll
        for (int off = 1; off < 64; off <<= 1) {
            int t = __shfl_up(inc, off);
            if (lane >= off) inc += t;
        }
        int pos = inc - cnt;
        if (f0) fA[pos++] = c0 + 0;
        if (f1) fA[pos++] = c0 + 1;
        if (f2) fA[pos++] = c0 + 2;
        if (f3) fA[pos++] = c0 + 3;
        nfree = __builtin_amdgcn_readlane(inc, 63);
    }
    __syncthreads();

    // ---- phase 2: JV augmenting row reduction (2 passes, integer-exact) ----
    int* fcur = fA;
    int* fnxt = fB;
    for (int pass = 0; pass < 2 && nfree > 0; ++pass) {
        int k = 0, n2 = 0;
        while (k < nfree) {
            int i = fcur[k]; k++;
            ushort4 cq = *(const ushort4*)(Q + i * N + c0);
            u32 q0p = ((u32)((int)cq.x - v0) << 8) | (u32)(c0 + 0);
            u32 q1p = ((u32)((int)cq.y - v1) << 8) | (u32)(c0 + 1);
            u32 q2p = ((u32)((int)cq.z - v2) << 8) | (u32)(c0 + 2);
            u32 q3p = ((u32)((int)cq.w - v3) << 8) | (u32)(c0 + 3);
            u32 m01 = umin2(q0p, q1p), M01 = umax2(q0p, q1p);
            u32 m23 = umin2(q2p, q3p), M23 = umax2(q2p, q3p);
            u32 P1 = umin2(m01, m23);
            u32 P2 = umin2(umax2(m01, m23), umin2(M01, M23));
            wave_min2_64(P1, P2);
            int u1 = (int)(P1 >> 8), j1 = (int)(P1 & 255);
            int u2 = (int)(P2 >> 8), j2 = (int)(P2 & 255);
            int i0 = row4col[j1];
            if (u1 < u2) {
                int d = u2 - u1, ow = j1 >> 2, sl = j1 & 3;
                if (lane == ow) {
                    if (sl == 0) v0 -= d; else if (sl == 1) v1 -= d;
                    else if (sl == 2) v2 -= d; else v3 -= d;
                }
            } else if (i0 >= 0) {
                j1 = j2;
                i0 = row4col[j2];
            }
            if (lane == 0) { row4col[j1] = i; col4row[i] = j1; u_lds[i] = u2; }
            if (i0 >= 0) {
                if (lane == 0) col4row[i0] = -1;
                if (u1 < u2) { k--; if (lane == 0) fcur[k] = i0; }
                else         { if (lane == 0) fnxt[n2] = i0; n2++; }
            }
            __syncthreads();
        }
        int* t = fcur; fcur = fnxt; fnxt = t;
        nfree = n2;
    }

    // reload register copy of row4col for owned columns
    { int4 rr = *(const int4*)&row4col[c0]; r0 = rr.x; r1 = rr.y; r2 = rr.z; r3 = rr.w; }

    // ---- phase 3: shortest augmenting path for remaining free rows ----
    const int INF0 = 0x00FFFFFF;
    for (int fi = 0; fi < nfree; ++fi) {
        int cur = fcur[fi];
        int sp0 = INF0, sp1 = INF0, sp2 = INF0, sp3 = INF0;
        int pp0 = -1, pp1 = -1, pp2 = -1, pp3 = -1;
        int scm = 0, minVal = 0, i = cur, nvis = 0, sink;

        for (;;) {
            if (lane == 0) vis[nvis] = i;
            nvis++;
            int ui = u_lds[i];                                   // uniform read
            ushort4 cq = *(const ushort4*)(Q + i * N + c0);      // ds_read_b64
            int base = minVal - ui;
            int r;
            r = base + (int)cq.x - v0; if (!(scm & 1) && r < sp0) { sp0 = r; pp0 = i; }
            r = base + (int)cq.y - v1; if (!(scm & 2) && r < sp1) { sp1 = r; pp1 = i; }
            r = base + (int)cq.z - v2; if (!(scm & 4) && r < sp2) { sp2 = r; pp2 = i; }
            r = base + (int)cq.w - v3; if (!(scm & 8) && r < sp3) { sp3 = r; pp3 = i; }

            u32 pk0 = (scm & 1) ? 0xFFFFFFFFu : (((u32)sp0 << 8) | (u32)(c0 + 0));
            u32 pk1 = (scm & 2) ? 0xFFFFFFFFu : (((u32)sp1 << 8) | (u32)(c0 + 1));
            u32 pk2 = (scm & 4) ? 0xFFFFFFFFu : (((u32)sp2 << 8) | (u32)(c0 + 2));
            u32 pk3 = (scm & 8) ? 0xFFFFFFFFu : (((u32)sp3 << 8) | (u32)(c0 + 3));
            u32 best = wave_min64(umin2(umin2(pk0, pk1), umin2(pk2, pk3)));
            minVal = (int)(best >> 8);
            int j = (int)(best & 255), sl = j & 3, ow = j >> 2;
            if (lane == ow) scm |= (1 << sl);
            int rjc = (sl == 0) ? r0 : ((sl == 1) ? r1 : ((sl == 2) ? r2 : r3));
            int rj = __builtin_amdgcn_readlane(rjc, ow);
            if (rj < 0) { sink = j; break; }
            i = rj;
        }

        *(int4*)&spc_lds[c0]  = make_int4(sp0, sp1, sp2, sp3);
        *(int4*)&path_lds[c0] = make_int4(pp0, pp1, pp2, pp3);
        __syncthreads();

        // dual update (scipy-identical, integer-exact)
        for (int k = lane; k < nvis; k += 64) {
            int rr = vis[k];
            if (rr != cur) u_lds[rr] += minVal - spc_lds[col4row[rr]];
        }
        if (lane == 0) u_lds[cur] += minVal;
        if (scm & 1) v0 += sp0 - minVal;
        if (scm & 2) v1 += sp1 - minVal;
        if (scm & 4) v2 += sp2 - minVal;
        if (scm & 8) v3 += sp3 - minVal;
        __syncthreads();

        // augment along predecessor path (lane 0)
        if (lane == 0) {
            int j = sink;
            for (;;) {
                int ii = path_lds[j];
                row4col[j] = ii;
                int jn = col4row[ii];
                col4row[ii] = j;
                if (ii == cur) break;
                j = jn;
            }
        }
        __syncthreads();
        int4 rr = *(const int4*)&row4col[c0];
        r0 = rr.x; r1 = rr.y; r2 = rr.z; r3 = rr.w;
    }

    // ---- per-sample mean of matched ORIGINAL fp32 costs ----
    __syncthreads();
    int4 cc = *(const int4*)&col4row[c0];
    float s = C[(size_t)(c0 + 0) * N + cc.x] + C[(size_t)(c0 + 1) * N + cc.y]
            + C[(size_t)(c0 + 2) * N + cc.z] + C[(size_t)(c0 + 3) * N + cc.w];
    s += __shfl_xor(s, 1);  s += __shfl_xor(s, 2);  s += __shfl_xor(s, 4);
    s += __shfl_xor(s, 8);  s += __shfl_xor(s, 16); s += __shfl_xor(s, 32);
    if (lane == 0) partial[b] = s * (1.0f / N);
}

__global__ __launch_bounds__(256, 1) void reduce_final(const float* __restrict__ partial,
                                                       float* __restrict__ out, int B) {
    const int t = threadIdx.x;
    __shared__ float rv[4];
    float s = (t < B) ? partial[t] : 0.0f;
    #pragma unroll
    for (int off = 32; off > 0; off >>= 1) s += __shfl_down(s, off);
    if ((t & 63) == 0) rv[t >> 6] = s;
    __syncthreads();
    if (t == 0) out[0] = (rv[0] + rv[1] + rv[2] + rv[3]) / (float)B;
}

extern "C" void kernel_launch(void* const* d_in, const int* in_sizes, int n_in,
                              void* d_out, int out_size, void* d_ws, size_t ws_size,
                              hipStream_t stream) {
    const float* D = (const float*)d_in[0];
    float* out = (float*)d_out;
    float* partial = (float*)d_ws;                 // B floats of scratch

    const int B = in_sizes[0] / (N * N);           // 256

    lap_solve<<<B, 64, 0, stream>>>(D, partial);
    reduce_final<<<1, 256, 0, stream>>>(partial, out, B);
}